// Round 7
// baseline (2406.531 us; speedup 1.0000x reference)
//
#include <hip/hip_runtime.h>

// ---------------------------------------------------------------------------
// EGNN scoring model, MI355X (gfx950).
// R7: edge kernel v3 — single structural change vs passing R6.
//   - WdT stored t-major [21][640] in LDS -> conflict-free lane-consecutive
//     reads (R6 had 1.48e8 bank-conflict cycles from stride-22 rows).
//   - 4 edges per wave: each WdT read feeds 4 h-FMAs (df in VGPRs),
//     4x less LDS traffic per (edge,e) pair.
//   - Same fp op order as passing R5/R6 (sinf/cosf, h = S + ascending-t dot,
//     per-lane e-stride accumulation, identical butterfly) -> z bit-identical.
// Everything else byte-identical to passing R6.
// ---------------------------------------------------------------------------

typedef unsigned int u32;
typedef unsigned long long u64;

#define NB 16
#define NN 2048
#define DD 142
#define KNNK 10
#define NNODES (NB * NN)        // 32768
#define NEDGES (NNODES * KNNK)  // 327680
#define E1OUT 610
#define APITCH 640

__device__ __forceinline__ float siluf(float x) { return x / (1.0f + __expf(-x)); }

__device__ __forceinline__ u64 wave_min_u64(u64 v) {
#pragma unroll
  for (int off = 32; off >= 1; off >>= 1) {
    u32 lo = (u32)v, hi = (u32)(v >> 32);
    u32 olo = (u32)__shfl_xor((int)lo, off, 64);
    u32 ohi = (u32)__shfl_xor((int)hi, off, 64);
    u64 o = ((u64)ohi << 32) | (u64)olo;
    v = (o < v) ? o : v;
  }
  return v;
}

// ---------------------------------------------------------------------------
// Wave-parallel KNN (exonerated in R6, unchanged).
// ---------------------------------------------------------------------------
__global__ __launch_bounds__(256) void knn_kernel(const float* __restrict__ coors,
                                                  int* __restrict__ idxo,
                                                  float* __restrict__ disto) {
  __shared__ float cl[NN * 3];
  int b = blockIdx.x >> 9;
  int i0 = (blockIdx.x & 511) << 2;
  for (int t = threadIdx.x; t < NN * 3; t += 256) cl[t] = coors[b * NN * 3 + t];
  __syncthreads();
  int wave = threadIdx.x >> 6, lane = threadIdx.x & 63;
  int il = i0 + wave;
  float xi = cl[il * 3 + 0], yi = cl[il * 3 + 1], zi = cl[il * 3 + 2];
  u64 r[KNNK];
#pragma unroll
  for (int t = 0; t < KNNK; ++t) r[t] = ~0ull;
  for (int j0 = 0; j0 < NN; j0 += 64) {
    int j = j0 + lane;
    float dx = __fadd_rn(xi, -cl[j * 3 + 0]);
    float dy = __fadd_rn(yi, -cl[j * 3 + 1]);
    float dz = __fadd_rn(zi, -cl[j * 3 + 2]);
    float d2 = __fadd_rn(__fadd_rn(__fmul_rn(dx, dx), __fmul_rn(dy, dy)), __fmul_rn(dz, dz));
    u64 cand = ((u64)__float_as_uint(d2) << 32) | (u64)(u32)j;
    if (cand < r[KNNK - 1]) {
      r[KNNK - 1] = cand;
#pragma unroll
      for (int t = KNNK - 1; t > 0; --t) {
        if (r[t] < r[t - 1]) { u64 tmp = r[t - 1]; r[t - 1] = r[t]; r[t] = tmp; }
      }
    }
  }
  int gi = b * NN + il;
#pragma unroll
  for (int t = 0; t < KNNK; ++t) {
    u64 head = r[0];
    u64 m = wave_min_u64(head);
    if (lane == t) {
      idxo[(size_t)gi * KNNK + t] = b * NN + (int)(u32)(m & 0xffffffffu);
      disto[(size_t)gi * KNNK + t] = __uint_as_float((u32)(m >> 32));
    }
    if (head == m) {
#pragma unroll
      for (int q = 0; q < KNNK - 1; ++q) r[q] = r[q + 1];
      r[KNNK - 1] = ~0ull;
    }
  }
}

// ---------------------------------------------------------------------------
// Brute linear (passing, unchanged).
// ---------------------------------------------------------------------------
__global__ __launch_bounds__(256) void brute_lin(
    const float* __restrict__ X, int ldx, int K,
    const float* __restrict__ W, int ldw, int r0, int Ncols,
    const float* __restrict__ bias, const float* __restrict__ resid, int ldr,
    float* __restrict__ Y, int ldy, int doSilu) {
  __shared__ float Xs[8 * 284];
  int n0 = blockIdx.x * 8;
  int tid = threadIdx.x;
  for (int p = tid; p < 8 * K; p += 256) {
    int n = p / K, k = p - n * K;
    Xs[n * K + k] = X[(size_t)(n0 + n) * ldx + k];
  }
  __syncthreads();
  float acc[8][3];
#pragma unroll
  for (int n = 0; n < 8; ++n)
#pragma unroll
    for (int s = 0; s < 3; ++s) acc[n][s] = 0.0f;
  int e1 = tid + 256, e2 = tid + 512;
  for (int k = 0; k < K; ++k) {
    const float* wr = W + (size_t)(r0 + k) * ldw;
    float w0 = (tid < Ncols) ? wr[tid] : 0.0f;
    float w1 = (e1 < Ncols) ? wr[e1] : 0.0f;
    float w2 = (e2 < Ncols) ? wr[e2] : 0.0f;
#pragma unroll
    for (int n = 0; n < 8; ++n) {
      float xv = Xs[n * K + k];
      acc[n][0] += xv * w0;
      acc[n][1] += xv * w1;
      acc[n][2] += xv * w2;
    }
  }
#pragma unroll
  for (int n = 0; n < 8; ++n) {
#pragma unroll
    for (int s = 0; s < 3; ++s) {
      int e = tid + s * 256;
      if (e < Ncols) {
        float v = acc[n][s];
        if (bias) v += bias[e];
        if (doSilu) v = siluf(v);
        if (resid) v += resid[(size_t)(n0 + n) * ldr + e];
        Y[(size_t)(n0 + n) * ldy + e] = v;
      }
    }
  }
}

// ---------------------------------------------------------------------------
// Edge kernel v3: 512 threads = 8 waves, each wave owns 4 edges.
// WdT t-major (conflict-free), df[4][21] in VGPRs, W_e2 from global (L1).
// ---------------------------------------------------------------------------
struct EdgeV3Lds {
  float WdTm[21][640];  // t-major, zero-padded for e >= 610
  float BE2[16];
};  // 53824 B

__global__ __launch_bounds__(512) void edge_v3(
    const float* __restrict__ Ap, const float* __restrict__ Bmm,
    const int* __restrict__ idxE, const float* __restrict__ distE,
    const float* __restrict__ W_e1, const float* __restrict__ W_e2,
    const float* __restrict__ b_e2, float* __restrict__ m_i) {
  __shared__ EdgeV3Lds L;
  int tid = threadIdx.x;
  for (int p = tid; p < 21 * 640; p += 512) {
    int t = p / 640, e = p - t * 640;
    L.WdTm[t][e] = (e < E1OUT) ? W_e1[(284 + t) * E1OUT + e] : 0.0f;
  }
  if (tid < 16) L.BE2[tid] = b_e2[tid];
  __syncthreads();

  int wave = tid >> 6, lane = tid & 63;
  int E0 = (blockIdx.x * 8 + wave) * 4;  // 10240 blocks * 8 waves * 4 edges, exact

  int iN[4], jN[4];
  float d2e[4];
#pragma unroll
  for (int ed = 0; ed < 4; ++ed) {
    int E = E0 + ed;
    iN[ed] = E / 10;
    jN[ed] = idxE[E];
    d2e[ed] = distE[E];
  }

  // dist features in registers (same ops as passing R5/R6: sinf/cosf, d2/2^t)
  float df[4][21];
#pragma unroll
  for (int ed = 0; ed < 4; ++ed) {
    float d2 = d2e[ed];
#pragma unroll
    for (int t = 0; t < 10; ++t) df[ed][t] = sinf(d2 / (float)(1 << t));
#pragma unroll
    for (int t = 0; t < 10; ++t) df[ed][10 + t] = cosf(d2 / (float)(1 << t));
    df[ed][20] = d2;
  }

  const float* ar0 = Ap + (size_t)iN[0] * APITCH;
  const float* ar1 = Ap + (size_t)iN[1] * APITCH;
  const float* ar2 = Ap + (size_t)iN[2] * APITCH;
  const float* ar3 = Ap + (size_t)iN[3] * APITCH;
  const float* br0 = Bmm + (size_t)jN[0] * APITCH;
  const float* br1 = Bmm + (size_t)jN[1] * APITCH;
  const float* br2 = Bmm + (size_t)jN[2] * APITCH;
  const float* br3 = Bmm + (size_t)jN[3] * APITCH;

  float z[4][16];
#pragma unroll
  for (int ed = 0; ed < 4; ++ed)
#pragma unroll
    for (int c = 0; c < 16; ++c) z[ed][c] = 0.0f;

#pragma unroll 1
  for (int s = 0; s < 10; ++s) {
    int e = lane + 64 * s;
    bool act = (e < E1OUT);
    int ec = act ? e : 0;
    float wdt[21];
#pragma unroll
    for (int t = 0; t < 21; ++t) wdt[t] = L.WdTm[t][e];  // e<640, pad is 0
    const float4* w2r = (const float4*)(W_e2 + (size_t)ec * 16);
    float4 w2a = w2r[0], w2b = w2r[1], w2c = w2r[2], w2d = w2r[3];

    float hsv[4];
    {
      float h0 = ar0[e] + br0[e];
      float h1 = ar1[e] + br1[e];
      float h2 = ar2[e] + br2[e];
      float h3 = ar3[e] + br3[e];
#pragma unroll
      for (int t = 0; t < 21; ++t) {
        float w = wdt[t];
        h0 += df[0][t] * w;
        h1 += df[1][t] * w;
        h2 += df[2][t] * w;
        h3 += df[3][t] * w;
      }
      hsv[0] = act ? siluf(h0) : 0.0f;
      hsv[1] = act ? siluf(h1) : 0.0f;
      hsv[2] = act ? siluf(h2) : 0.0f;
      hsv[3] = act ? siluf(h3) : 0.0f;
    }
#pragma unroll
    for (int ed = 0; ed < 4; ++ed) {
      float hs = hsv[ed];
      z[ed][0] += hs * w2a.x;  z[ed][1] += hs * w2a.y;
      z[ed][2] += hs * w2a.z;  z[ed][3] += hs * w2a.w;
      z[ed][4] += hs * w2b.x;  z[ed][5] += hs * w2b.y;
      z[ed][6] += hs * w2b.z;  z[ed][7] += hs * w2b.w;
      z[ed][8] += hs * w2c.x;  z[ed][9] += hs * w2c.y;
      z[ed][10] += hs * w2c.z; z[ed][11] += hs * w2c.w;
      z[ed][12] += hs * w2d.x; z[ed][13] += hs * w2d.y;
      z[ed][14] += hs * w2d.z; z[ed][15] += hs * w2d.w;
    }
  }

  // butterfly-reduce each (ed,c); lane ed*16+c keeps its total (static select)
  float msel = 0.0f;
#pragma unroll
  for (int ed = 0; ed < 4; ++ed) {
#pragma unroll
    for (int c = 0; c < 16; ++c) {
      float v = z[ed][c];
#pragma unroll
      for (int off = 32; off >= 1; off >>= 1) v += __shfl_xor(v, off, 64);
      if (lane == ed * 16 + c) msel = v;
    }
  }
  int isel = (lane < 16) ? iN[0] : (lane < 32) ? iN[1] : (lane < 48) ? iN[2] : iN[3];
  float be2v = L.BE2[lane & 15];
  float m = siluf(msel + be2v);
  atomicAdd(&m_i[(size_t)isel * 16 + (lane & 15)], m);
}

// ---------------------------------------------------------------------------
// LayerNorm + concat m_i -> node_in[32768][160]  (unchanged)
// ---------------------------------------------------------------------------
__global__ __launch_bounds__(256) void node_prep(const float* __restrict__ feats,
                                                 const float* __restrict__ m_i,
                                                 const float* __restrict__ ln_g,
                                                 const float* __restrict__ ln_b,
                                                 float* __restrict__ node_in) {
  int wave = threadIdx.x >> 6, lane = threadIdx.x & 63;
  int i = blockIdx.x * 4 + wave;
  const float* fr = feats + (size_t)i * DD;
  float x0 = fr[lane];
  float x1 = fr[lane + 64];
  float x2 = (lane < 14) ? fr[lane + 128] : 0.0f;
  float s = x0 + x1 + x2;
#pragma unroll
  for (int off = 32; off >= 1; off >>= 1) s += __shfl_xor(s, off, 64);
  float mu = s / 142.0f;
  float d0 = x0 - mu, d1 = x1 - mu, d2 = (lane < 14) ? (x2 - mu) : 0.0f;
  float ss = d0 * d0 + d1 * d1 + d2 * d2;
#pragma unroll
  for (int off = 32; off >= 1; off >>= 1) ss += __shfl_xor(ss, off, 64);
  float var = ss / 142.0f;
  float rstd = 1.0f / sqrtf(var + 1e-5f);
  float* o = node_in + (size_t)i * 160;
  o[lane] = d0 * rstd * ln_g[lane] + ln_b[lane];
  o[lane + 64] = d1 * rstd * ln_g[lane + 64] + ln_b[lane + 64];
  if (lane < 14) o[lane + 128] = d2 * rstd * ln_g[lane + 128] + ln_b[lane + 128];
  if (lane < 16) o[142 + lane] = m_i[i * 16 + lane];
}

// ---------------------------------------------------------------------------
// Masked mean pool fused with head -> f32 emb accumulator (unchanged)
// ---------------------------------------------------------------------------
__global__ __launch_bounds__(256) void pool_kernel(const float* __restrict__ node_out,
                                                   const float* __restrict__ W_out,
                                                   const float* __restrict__ b_out,
                                                   float* __restrict__ emb) {
  int b = blockIdx.x, chunk = blockIdx.y;
  int d = threadIdx.x;
  float acc = 0.0f;
  if (d < DD) {
    const float* base = node_out + ((size_t)(b * NN + chunk * 256)) * 144 + d;
    for (int n = 0; n < 256; ++n) acc += base[(size_t)n * 144];
    acc = acc * W_out[d] * (1.0f / 2048.0f);
  }
  __shared__ float red[256];
  red[threadIdx.x] = acc;
  __syncthreads();
  for (int off = 128; off >= 1; off >>= 1) {
    if (threadIdx.x < off) red[threadIdx.x] += red[threadIdx.x + off];
    __syncthreads();
  }
  if (threadIdx.x == 0) {
    float v = red[0];
    if (chunk == 0) v += b_out[0];
    atomicAdd(&emb[b], v);
  }
}

__global__ void finalize_kernel(const float* __restrict__ emb, float* __restrict__ outp) {
  int t = threadIdx.x;
  if (t < NB) outp[t] = emb[t];
}

// ---------------------------------------------------------------------------
extern "C" void kernel_launch(void* const* d_in, const int* in_sizes, int n_in,
                              void* d_out, int out_size, void* d_ws, size_t ws_size,
                              hipStream_t stream) {
  const float* feats = (const float*)d_in[0];
  const float* coors = (const float*)d_in[1];
  const float* W_e1 = (const float*)d_in[3];
  const float* b_e1 = (const float*)d_in[4];
  const float* W_e2 = (const float*)d_in[5];
  const float* b_e2 = (const float*)d_in[6];
  const float* ln_g = (const float*)d_in[11];
  const float* ln_b = (const float*)d_in[12];
  const float* W_n1 = (const float*)d_in[13];
  const float* b_n1 = (const float*)d_in[14];
  const float* W_n2 = (const float*)d_in[15];
  const float* b_n2 = (const float*)d_in[16];
  const float* W_out = (const float*)d_in[17];
  const float* b_out = (const float*)d_in[18];
  float* out = (float*)d_out;

  char* ws = (char*)d_ws;
  const size_t OFF_IDX = 0;
  const size_t OFF_DIST = 1310720;
  const size_t OFF_MI = 2621440;
  const size_t OFF_AP = 4718592;
  const size_t OFF_BM = 88604672;
  const size_t OFF_NIN = OFF_AP;              // reuse after edge kernel
  const size_t OFF_HN = OFF_AP + 20971520;
  const size_t OFF_NOUT = OFF_HN + 37748736;
  const size_t OFF_EMB = 172490752;

  int* idx = (int*)(ws + OFF_IDX);
  float* dist = (float*)(ws + OFF_DIST);
  float* m_i = (float*)(ws + OFF_MI);
  float* Ap = (float*)(ws + OFF_AP);
  float* Bm = (float*)(ws + OFF_BM);
  float* node_in = (float*)(ws + OFF_NIN);
  float* hnode = (float*)(ws + OFF_HN);
  float* node_out = (float*)(ws + OFF_NOUT);
  float* emb = (float*)(ws + OFF_EMB);

  hipMemsetAsync(m_i, 0, (size_t)NNODES * 16 * 4, stream);
  hipMemsetAsync(emb, 0, (size_t)NB * 4, stream);

  knn_kernel<<<dim3(NB * 512), dim3(256), 0, stream>>>(coors, idx, dist);

  brute_lin<<<dim3(NNODES / 8), dim3(256), 0, stream>>>(
      feats, DD, DD, W_e1, E1OUT, 0, E1OUT, b_e1, nullptr, 0, Ap, APITCH, 0);
  brute_lin<<<dim3(NNODES / 8), dim3(256), 0, stream>>>(
      feats, DD, DD, W_e1, E1OUT, 142, E1OUT, nullptr, nullptr, 0, Bm, APITCH, 0);

  edge_v3<<<dim3(NEDGES / 32), dim3(512), 0, stream>>>(
      Ap, Bm, idx, dist, W_e1, W_e2, b_e2, m_i);

  node_prep<<<dim3(NNODES / 4), dim3(256), 0, stream>>>(feats, m_i, ln_g, ln_b, node_in);

  brute_lin<<<dim3(NNODES / 8), dim3(256), 0, stream>>>(
      node_in, 160, 158, W_n1, 284, 0, 284, b_n1, nullptr, 0, hnode, 288, 1);
  brute_lin<<<dim3(NNODES / 8), dim3(256), 0, stream>>>(
      hnode, 288, 284, W_n2, DD, 0, DD, b_n2, feats, DD, node_out, 144, 0);

  pool_kernel<<<dim3(NB, 8), dim3(256), 0, stream>>>(node_out, W_out, b_out, emb);

  finalize_kernel<<<dim3(1), dim3(64), 0, stream>>>(emb, out);
}

// Round 8
// 2394.736 us; speedup vs baseline: 1.0049x; 1.0049x over previous
//
#include <hip/hip_runtime.h>

// ---------------------------------------------------------------------------
// EGNN scoring model, MI355X (gfx950).
// R8: edge kernel v4 — fix R7's register spill (VGPR demand ~180 @ cap 128 ->
// 3.1 GB scratch traffic). Now 2 edges/wave (df[2][21]+z[2][16] ~ 110 VGPR),
// t-major WdT kept (bank-conflict-free; R7 proved conflicts -> 0), wdt read
// inline (ds_read immediate offsets t*2560, no staging array).
// Math identical op-for-op to passing R5/R6/R7. Everything else unchanged.
// ---------------------------------------------------------------------------

typedef unsigned int u32;
typedef unsigned long long u64;

#define NB 16
#define NN 2048
#define DD 142
#define KNNK 10
#define NNODES (NB * NN)        // 32768
#define NEDGES (NNODES * KNNK)  // 327680
#define E1OUT 610
#define APITCH 640

__device__ __forceinline__ float siluf(float x) { return x / (1.0f + __expf(-x)); }

__device__ __forceinline__ u64 wave_min_u64(u64 v) {
#pragma unroll
  for (int off = 32; off >= 1; off >>= 1) {
    u32 lo = (u32)v, hi = (u32)(v >> 32);
    u32 olo = (u32)__shfl_xor((int)lo, off, 64);
    u32 ohi = (u32)__shfl_xor((int)hi, off, 64);
    u64 o = ((u64)ohi << 32) | (u64)olo;
    v = (o < v) ? o : v;
  }
  return v;
}

// ---------------------------------------------------------------------------
// Wave-parallel KNN (proven, unchanged).
// ---------------------------------------------------------------------------
__global__ __launch_bounds__(256) void knn_kernel(const float* __restrict__ coors,
                                                  int* __restrict__ idxo,
                                                  float* __restrict__ disto) {
  __shared__ float cl[NN * 3];
  int b = blockIdx.x >> 9;
  int i0 = (blockIdx.x & 511) << 2;
  for (int t = threadIdx.x; t < NN * 3; t += 256) cl[t] = coors[b * NN * 3 + t];
  __syncthreads();
  int wave = threadIdx.x >> 6, lane = threadIdx.x & 63;
  int il = i0 + wave;
  float xi = cl[il * 3 + 0], yi = cl[il * 3 + 1], zi = cl[il * 3 + 2];
  u64 r[KNNK];
#pragma unroll
  for (int t = 0; t < KNNK; ++t) r[t] = ~0ull;
  for (int j0 = 0; j0 < NN; j0 += 64) {
    int j = j0 + lane;
    float dx = __fadd_rn(xi, -cl[j * 3 + 0]);
    float dy = __fadd_rn(yi, -cl[j * 3 + 1]);
    float dz = __fadd_rn(zi, -cl[j * 3 + 2]);
    float d2 = __fadd_rn(__fadd_rn(__fmul_rn(dx, dx), __fmul_rn(dy, dy)), __fmul_rn(dz, dz));
    u64 cand = ((u64)__float_as_uint(d2) << 32) | (u64)(u32)j;
    if (cand < r[KNNK - 1]) {
      r[KNNK - 1] = cand;
#pragma unroll
      for (int t = KNNK - 1; t > 0; --t) {
        if (r[t] < r[t - 1]) { u64 tmp = r[t - 1]; r[t - 1] = r[t]; r[t] = tmp; }
      }
    }
  }
  int gi = b * NN + il;
#pragma unroll
  for (int t = 0; t < KNNK; ++t) {
    u64 head = r[0];
    u64 m = wave_min_u64(head);
    if (lane == t) {
      idxo[(size_t)gi * KNNK + t] = b * NN + (int)(u32)(m & 0xffffffffu);
      disto[(size_t)gi * KNNK + t] = __uint_as_float((u32)(m >> 32));
    }
    if (head == m) {
#pragma unroll
      for (int q = 0; q < KNNK - 1; ++q) r[q] = r[q + 1];
      r[KNNK - 1] = ~0ull;
    }
  }
}

// ---------------------------------------------------------------------------
// Brute linear (proven, unchanged).
// ---------------------------------------------------------------------------
__global__ __launch_bounds__(256) void brute_lin(
    const float* __restrict__ X, int ldx, int K,
    const float* __restrict__ W, int ldw, int r0, int Ncols,
    const float* __restrict__ bias, const float* __restrict__ resid, int ldr,
    float* __restrict__ Y, int ldy, int doSilu) {
  __shared__ float Xs[8 * 284];
  int n0 = blockIdx.x * 8;
  int tid = threadIdx.x;
  for (int p = tid; p < 8 * K; p += 256) {
    int n = p / K, k = p - n * K;
    Xs[n * K + k] = X[(size_t)(n0 + n) * ldx + k];
  }
  __syncthreads();
  float acc[8][3];
#pragma unroll
  for (int n = 0; n < 8; ++n)
#pragma unroll
    for (int s = 0; s < 3; ++s) acc[n][s] = 0.0f;
  int e1 = tid + 256, e2 = tid + 512;
  for (int k = 0; k < K; ++k) {
    const float* wr = W + (size_t)(r0 + k) * ldw;
    float w0 = (tid < Ncols) ? wr[tid] : 0.0f;
    float w1 = (e1 < Ncols) ? wr[e1] : 0.0f;
    float w2 = (e2 < Ncols) ? wr[e2] : 0.0f;
#pragma unroll
    for (int n = 0; n < 8; ++n) {
      float xv = Xs[n * K + k];
      acc[n][0] += xv * w0;
      acc[n][1] += xv * w1;
      acc[n][2] += xv * w2;
    }
  }
#pragma unroll
  for (int n = 0; n < 8; ++n) {
#pragma unroll
    for (int s = 0; s < 3; ++s) {
      int e = tid + s * 256;
      if (e < Ncols) {
        float v = acc[n][s];
        if (bias) v += bias[e];
        if (doSilu) v = siluf(v);
        if (resid) v += resid[(size_t)(n0 + n) * ldr + e];
        Y[(size_t)(n0 + n) * ldy + e] = v;
      }
    }
  }
}

// ---------------------------------------------------------------------------
// Edge kernel v4: 512 threads = 8 waves, each wave owns 2 edges.
// t-major WdT in LDS (conflict-free); df[2][21] + z[2][16] in VGPRs (~110,
// no spill); W_e2 float4 loads shared across the 2 edges.
// ---------------------------------------------------------------------------
struct EdgeV4Lds {
  float WdTm[21][640];  // t-major, zero-padded for e >= 610
  float BE2[16];
};  // 53824 B

__global__ __launch_bounds__(512) void edge_v4(
    const float* __restrict__ Ap, const float* __restrict__ Bmm,
    const int* __restrict__ idxE, const float* __restrict__ distE,
    const float* __restrict__ W_e1, const float* __restrict__ W_e2,
    const float* __restrict__ b_e2, float* __restrict__ m_i) {
  __shared__ EdgeV4Lds L;
  int tid = threadIdx.x;
  for (int p = tid; p < 21 * 640; p += 512) {
    int t = p / 640, e = p - t * 640;
    L.WdTm[t][e] = (e < E1OUT) ? W_e1[(284 + t) * E1OUT + e] : 0.0f;
  }
  if (tid < 16) L.BE2[tid] = b_e2[tid];
  __syncthreads();

  int wave = tid >> 6, lane = tid & 63;
  int E0 = (blockIdx.x * 8 + wave) * 2;  // 20480 blocks * 8 waves * 2 edges

  int i0 = E0 / 10, i1 = (E0 + 1) / 10;
  int j0 = idxE[E0], j1 = idxE[E0 + 1];
  float d20 = distE[E0], d21 = distE[E0 + 1];

  // dist features in registers (same ops as passing rounds)
  float df0[21], df1[21];
#pragma unroll
  for (int t = 0; t < 10; ++t) df0[t] = sinf(d20 / (float)(1 << t));
#pragma unroll
  for (int t = 0; t < 10; ++t) df0[10 + t] = cosf(d20 / (float)(1 << t));
  df0[20] = d20;
#pragma unroll
  for (int t = 0; t < 10; ++t) df1[t] = sinf(d21 / (float)(1 << t));
#pragma unroll
  for (int t = 0; t < 10; ++t) df1[10 + t] = cosf(d21 / (float)(1 << t));
  df1[20] = d21;

  const float* ar0 = Ap + (size_t)i0 * APITCH;
  const float* ar1 = Ap + (size_t)i1 * APITCH;
  const float* br0 = Bmm + (size_t)j0 * APITCH;
  const float* br1 = Bmm + (size_t)j1 * APITCH;

  float z0[16], z1[16];
#pragma unroll
  for (int c = 0; c < 16; ++c) { z0[c] = 0.0f; z1[c] = 0.0f; }

  const float* wcol = &L.WdTm[0][0];
#pragma unroll 1
  for (int s = 0; s < 10; ++s) {
    int e = lane + 64 * s;
    bool act = (e < E1OUT);
    int ec = act ? e : 0;

    float h0 = ar0[e] + br0[e];
    float h1 = ar1[e] + br1[e];
#pragma unroll
    for (int t = 0; t < 21; ++t) {
      float w = wcol[t * 640 + e];  // ds_read base+imm(t*2560), conflict-free
      h0 += df0[t] * w;
      h1 += df1[t] * w;
    }
    float hs0 = act ? siluf(h0) : 0.0f;
    float hs1 = act ? siluf(h1) : 0.0f;

    const float4* w2r = (const float4*)(W_e2 + (size_t)ec * 16);
    float4 w2a = w2r[0], w2b = w2r[1], w2c = w2r[2], w2d = w2r[3];
    z0[0] += hs0 * w2a.x;  z0[1] += hs0 * w2a.y;  z0[2] += hs0 * w2a.z;  z0[3] += hs0 * w2a.w;
    z0[4] += hs0 * w2b.x;  z0[5] += hs0 * w2b.y;  z0[6] += hs0 * w2b.z;  z0[7] += hs0 * w2b.w;
    z0[8] += hs0 * w2c.x;  z0[9] += hs0 * w2c.y;  z0[10] += hs0 * w2c.z; z0[11] += hs0 * w2c.w;
    z0[12] += hs0 * w2d.x; z0[13] += hs0 * w2d.y; z0[14] += hs0 * w2d.z; z0[15] += hs0 * w2d.w;
    z1[0] += hs1 * w2a.x;  z1[1] += hs1 * w2a.y;  z1[2] += hs1 * w2a.z;  z1[3] += hs1 * w2a.w;
    z1[4] += hs1 * w2b.x;  z1[5] += hs1 * w2b.y;  z1[6] += hs1 * w2b.z;  z1[7] += hs1 * w2b.w;
    z1[8] += hs1 * w2c.x;  z1[9] += hs1 * w2c.y;  z1[10] += hs1 * w2c.z; z1[11] += hs1 * w2c.w;
    z1[12] += hs1 * w2d.x; z1[13] += hs1 * w2d.y; z1[14] += hs1 * w2d.z; z1[15] += hs1 * w2d.w;
  }

  // butterfly-reduce each (ed,c); lane ed*16+c keeps its total
  float msel = 0.0f;
#pragma unroll
  for (int c = 0; c < 16; ++c) {
    float v = z0[c];
#pragma unroll
    for (int off = 32; off >= 1; off >>= 1) v += __shfl_xor(v, off, 64);
    if (lane == c) msel = v;
  }
#pragma unroll
  for (int c = 0; c < 16; ++c) {
    float v = z1[c];
#pragma unroll
    for (int off = 32; off >= 1; off >>= 1) v += __shfl_xor(v, off, 64);
    if (lane == 16 + c) msel = v;
  }
  if (lane < 32) {
    int isel = (lane < 16) ? i0 : i1;
    float m = siluf(msel + L.BE2[lane & 15]);
    atomicAdd(&m_i[(size_t)isel * 16 + (lane & 15)], m);
  }
}

// ---------------------------------------------------------------------------
// LayerNorm + concat m_i -> node_in[32768][160]  (unchanged)
// ---------------------------------------------------------------------------
__global__ __launch_bounds__(256) void node_prep(const float* __restrict__ feats,
                                                 const float* __restrict__ m_i,
                                                 const float* __restrict__ ln_g,
                                                 const float* __restrict__ ln_b,
                                                 float* __restrict__ node_in) {
  int wave = threadIdx.x >> 6, lane = threadIdx.x & 63;
  int i = blockIdx.x * 4 + wave;
  const float* fr = feats + (size_t)i * DD;
  float x0 = fr[lane];
  float x1 = fr[lane + 64];
  float x2 = (lane < 14) ? fr[lane + 128] : 0.0f;
  float s = x0 + x1 + x2;
#pragma unroll
  for (int off = 32; off >= 1; off >>= 1) s += __shfl_xor(s, off, 64);
  float mu = s / 142.0f;
  float d0 = x0 - mu, d1 = x1 - mu, d2 = (lane < 14) ? (x2 - mu) : 0.0f;
  float ss = d0 * d0 + d1 * d1 + d2 * d2;
#pragma unroll
  for (int off = 32; off >= 1; off >>= 1) ss += __shfl_xor(ss, off, 64);
  float var = ss / 142.0f;
  float rstd = 1.0f / sqrtf(var + 1e-5f);
  float* o = node_in + (size_t)i * 160;
  o[lane] = d0 * rstd * ln_g[lane] + ln_b[lane];
  o[lane + 64] = d1 * rstd * ln_g[lane + 64] + ln_b[lane + 64];
  if (lane < 14) o[lane + 128] = d2 * rstd * ln_g[lane + 128] + ln_b[lane + 128];
  if (lane < 16) o[142 + lane] = m_i[i * 16 + lane];
}

// ---------------------------------------------------------------------------
// Masked mean pool fused with head -> f32 emb accumulator (unchanged)
// ---------------------------------------------------------------------------
__global__ __launch_bounds__(256) void pool_kernel(const float* __restrict__ node_out,
                                                   const float* __restrict__ W_out,
                                                   const float* __restrict__ b_out,
                                                   float* __restrict__ emb) {
  int b = blockIdx.x, chunk = blockIdx.y;
  int d = threadIdx.x;
  float acc = 0.0f;
  if (d < DD) {
    const float* base = node_out + ((size_t)(b * NN + chunk * 256)) * 144 + d;
    for (int n = 0; n < 256; ++n) acc += base[(size_t)n * 144];
    acc = acc * W_out[d] * (1.0f / 2048.0f);
  }
  __shared__ float red[256];
  red[threadIdx.x] = acc;
  __syncthreads();
  for (int off = 128; off >= 1; off >>= 1) {
    if (threadIdx.x < off) red[threadIdx.x] += red[threadIdx.x + off];
    __syncthreads();
  }
  if (threadIdx.x == 0) {
    float v = red[0];
    if (chunk == 0) v += b_out[0];
    atomicAdd(&emb[b], v);
  }
}

__global__ void finalize_kernel(const float* __restrict__ emb, float* __restrict__ outp) {
  int t = threadIdx.x;
  if (t < NB) outp[t] = emb[t];
}

// ---------------------------------------------------------------------------
extern "C" void kernel_launch(void* const* d_in, const int* in_sizes, int n_in,
                              void* d_out, int out_size, void* d_ws, size_t ws_size,
                              hipStream_t stream) {
  const float* feats = (const float*)d_in[0];
  const float* coors = (const float*)d_in[1];
  const float* W_e1 = (const float*)d_in[3];
  const float* b_e1 = (const float*)d_in[4];
  const float* W_e2 = (const float*)d_in[5];
  const float* b_e2 = (const float*)d_in[6];
  const float* ln_g = (const float*)d_in[11];
  const float* ln_b = (const float*)d_in[12];
  const float* W_n1 = (const float*)d_in[13];
  const float* b_n1 = (const float*)d_in[14];
  const float* W_n2 = (const float*)d_in[15];
  const float* b_n2 = (const float*)d_in[16];
  const float* W_out = (const float*)d_in[17];
  const float* b_out = (const float*)d_in[18];
  float* out = (float*)d_out;

  char* ws = (char*)d_ws;
  const size_t OFF_IDX = 0;
  const size_t OFF_DIST = 1310720;
  const size_t OFF_MI = 2621440;
  const size_t OFF_AP = 4718592;
  const size_t OFF_BM = 88604672;
  const size_t OFF_NIN = OFF_AP;              // reuse after edge kernel
  const size_t OFF_HN = OFF_AP + 20971520;
  const size_t OFF_NOUT = OFF_HN + 37748736;
  const size_t OFF_EMB = 172490752;

  int* idx = (int*)(ws + OFF_IDX);
  float* dist = (float*)(ws + OFF_DIST);
  float* m_i = (float*)(ws + OFF_MI);
  float* Ap = (float*)(ws + OFF_AP);
  float* Bm = (float*)(ws + OFF_BM);
  float* node_in = (float*)(ws + OFF_NIN);
  float* hnode = (float*)(ws + OFF_HN);
  float* node_out = (float*)(ws + OFF_NOUT);
  float* emb = (float*)(ws + OFF_EMB);

  hipMemsetAsync(m_i, 0, (size_t)NNODES * 16 * 4, stream);
  hipMemsetAsync(emb, 0, (size_t)NB * 4, stream);

  knn_kernel<<<dim3(NB * 512), dim3(256), 0, stream>>>(coors, idx, dist);

  brute_lin<<<dim3(NNODES / 8), dim3(256), 0, stream>>>(
      feats, DD, DD, W_e1, E1OUT, 0, E1OUT, b_e1, nullptr, 0, Ap, APITCH, 0);
  brute_lin<<<dim3(NNODES / 8), dim3(256), 0, stream>>>(
      feats, DD, DD, W_e1, E1OUT, 142, E1OUT, nullptr, nullptr, 0, Bm, APITCH, 0);

  edge_v4<<<dim3(NEDGES / 16), dim3(512), 0, stream>>>(
      Ap, Bm, idx, dist, W_e1, W_e2, b_e2, m_i);

  node_prep<<<dim3(NNODES / 4), dim3(256), 0, stream>>>(feats, m_i, ln_g, ln_b, node_in);

  brute_lin<<<dim3(NNODES / 8), dim3(256), 0, stream>>>(
      node_in, 160, 158, W_n1, 284, 0, 284, b_n1, nullptr, 0, hnode, 288, 1);
  brute_lin<<<dim3(NNODES / 8), dim3(256), 0, stream>>>(
      hnode, 288, 284, W_n2, DD, 0, DD, b_n2, feats, DD, node_out, 144, 0);

  pool_kernel<<<dim3(NB, 8), dim3(256), 0, stream>>>(node_out, W_out, b_out, emb);

  finalize_kernel<<<dim3(1), dim3(64), 0, stream>>>(emb, out);
}

// Round 10
// 1722.811 us; speedup vs baseline: 1.3969x; 1.3900x over previous
//
#include <hip/hip_runtime.h>

// ---------------------------------------------------------------------------
// EGNN scoring model, MI355X (gfx950).
// R10: edge kernel v6 — zero-LDS edge kernel, Wd read DIRECTLY from W_e1
// (rows 284..304; lane-consecutive e -> coalesced dword loads, L1/L2-resident
// 51 KB). R9's failure was WgT scratch aliasing the live Ap region (offset
// 82.3MB inside Ap's 4.7..88.6MB) — no scratch table at all now, no prep
// kernel, no aliasing surface. Math op-for-op identical to passing R6/R8.
// Everything else byte-identical to passing R8.
// ---------------------------------------------------------------------------

typedef unsigned int u32;
typedef unsigned long long u64;

#define NB 16
#define NN 2048
#define DD 142
#define KNNK 10
#define NNODES (NB * NN)        // 32768
#define NEDGES (NNODES * KNNK)  // 327680
#define E1OUT 610
#define APITCH 640

__device__ __forceinline__ float siluf(float x) { return x / (1.0f + __expf(-x)); }

__device__ __forceinline__ u64 wave_min_u64(u64 v) {
#pragma unroll
  for (int off = 32; off >= 1; off >>= 1) {
    u32 lo = (u32)v, hi = (u32)(v >> 32);
    u32 olo = (u32)__shfl_xor((int)lo, off, 64);
    u32 ohi = (u32)__shfl_xor((int)hi, off, 64);
    u64 o = ((u64)ohi << 32) | (u64)olo;
    v = (o < v) ? o : v;
  }
  return v;
}

// ---------------------------------------------------------------------------
// Wave-parallel KNN (proven, unchanged).
// ---------------------------------------------------------------------------
__global__ __launch_bounds__(256) void knn_kernel(const float* __restrict__ coors,
                                                  int* __restrict__ idxo,
                                                  float* __restrict__ disto) {
  __shared__ float cl[NN * 3];
  int b = blockIdx.x >> 9;
  int i0 = (blockIdx.x & 511) << 2;
  for (int t = threadIdx.x; t < NN * 3; t += 256) cl[t] = coors[b * NN * 3 + t];
  __syncthreads();
  int wave = threadIdx.x >> 6, lane = threadIdx.x & 63;
  int il = i0 + wave;
  float xi = cl[il * 3 + 0], yi = cl[il * 3 + 1], zi = cl[il * 3 + 2];
  u64 r[KNNK];
#pragma unroll
  for (int t = 0; t < KNNK; ++t) r[t] = ~0ull;
  for (int j0 = 0; j0 < NN; j0 += 64) {
    int j = j0 + lane;
    float dx = __fadd_rn(xi, -cl[j * 3 + 0]);
    float dy = __fadd_rn(yi, -cl[j * 3 + 1]);
    float dz = __fadd_rn(zi, -cl[j * 3 + 2]);
    float d2 = __fadd_rn(__fadd_rn(__fmul_rn(dx, dx), __fmul_rn(dy, dy)), __fmul_rn(dz, dz));
    u64 cand = ((u64)__float_as_uint(d2) << 32) | (u64)(u32)j;
    if (cand < r[KNNK - 1]) {
      r[KNNK - 1] = cand;
#pragma unroll
      for (int t = KNNK - 1; t > 0; --t) {
        if (r[t] < r[t - 1]) { u64 tmp = r[t - 1]; r[t - 1] = r[t]; r[t] = tmp; }
      }
    }
  }
  int gi = b * NN + il;
#pragma unroll
  for (int t = 0; t < KNNK; ++t) {
    u64 head = r[0];
    u64 m = wave_min_u64(head);
    if (lane == t) {
      idxo[(size_t)gi * KNNK + t] = b * NN + (int)(u32)(m & 0xffffffffu);
      disto[(size_t)gi * KNNK + t] = __uint_as_float((u32)(m >> 32));
    }
    if (head == m) {
#pragma unroll
      for (int q = 0; q < KNNK - 1; ++q) r[q] = r[q + 1];
      r[KNNK - 1] = ~0ull;
    }
  }
}

// ---------------------------------------------------------------------------
// Brute linear (proven, unchanged).
// ---------------------------------------------------------------------------
__global__ __launch_bounds__(256) void brute_lin(
    const float* __restrict__ X, int ldx, int K,
    const float* __restrict__ W, int ldw, int r0, int Ncols,
    const float* __restrict__ bias, const float* __restrict__ resid, int ldr,
    float* __restrict__ Y, int ldy, int doSilu) {
  __shared__ float Xs[8 * 284];
  int n0 = blockIdx.x * 8;
  int tid = threadIdx.x;
  for (int p = tid; p < 8 * K; p += 256) {
    int n = p / K, k = p - n * K;
    Xs[n * K + k] = X[(size_t)(n0 + n) * ldx + k];
  }
  __syncthreads();
  float acc[8][3];
#pragma unroll
  for (int n = 0; n < 8; ++n)
#pragma unroll
    for (int s = 0; s < 3; ++s) acc[n][s] = 0.0f;
  int e1 = tid + 256, e2 = tid + 512;
  for (int k = 0; k < K; ++k) {
    const float* wr = W + (size_t)(r0 + k) * ldw;
    float w0 = (tid < Ncols) ? wr[tid] : 0.0f;
    float w1 = (e1 < Ncols) ? wr[e1] : 0.0f;
    float w2 = (e2 < Ncols) ? wr[e2] : 0.0f;
#pragma unroll
    for (int n = 0; n < 8; ++n) {
      float xv = Xs[n * K + k];
      acc[n][0] += xv * w0;
      acc[n][1] += xv * w1;
      acc[n][2] += xv * w2;
    }
  }
#pragma unroll
  for (int n = 0; n < 8; ++n) {
#pragma unroll
    for (int s = 0; s < 3; ++s) {
      int e = tid + s * 256;
      if (e < Ncols) {
        float v = acc[n][s];
        if (bias) v += bias[e];
        if (doSilu) v = siluf(v);
        if (resid) v += resid[(size_t)(n0 + n) * ldr + e];
        Y[(size_t)(n0 + n) * ldy + e] = v;
      }
    }
  }
}

// ---------------------------------------------------------------------------
// Edge kernel v6: 512 threads = 8 waves, 2 edges/wave, ZERO LDS, no scratch.
// Wd rows read directly from W_e1 (coalesced dword per t, L1/L2-resident).
// Same math order as passing rounds -> bit-identical z.
// ---------------------------------------------------------------------------
__global__ __launch_bounds__(512, 4) void edge_v6(
    const float* __restrict__ Ap, const float* __restrict__ Bmm,
    const int* __restrict__ idxE, const float* __restrict__ distE,
    const float* __restrict__ W_e1, const float* __restrict__ W_e2,
    const float* __restrict__ b_e2, float* __restrict__ m_i) {
  int tid = threadIdx.x;
  int wave = tid >> 6, lane = tid & 63;
  int E0 = (blockIdx.x * 8 + wave) * 2;  // 20480 blocks * 8 waves * 2 edges

  int i0 = E0 / 10, i1 = (E0 + 1) / 10;
  int j0 = idxE[E0], j1 = idxE[E0 + 1];
  float d20 = distE[E0], d21 = distE[E0 + 1];

  float df0[21], df1[21];
#pragma unroll
  for (int t = 0; t < 10; ++t) df0[t] = sinf(d20 / (float)(1 << t));
#pragma unroll
  for (int t = 0; t < 10; ++t) df0[10 + t] = cosf(d20 / (float)(1 << t));
  df0[20] = d20;
#pragma unroll
  for (int t = 0; t < 10; ++t) df1[t] = sinf(d21 / (float)(1 << t));
#pragma unroll
  for (int t = 0; t < 10; ++t) df1[10 + t] = cosf(d21 / (float)(1 << t));
  df1[20] = d21;

  const float* ar0 = Ap + (size_t)i0 * APITCH;
  const float* ar1 = Ap + (size_t)i1 * APITCH;
  const float* br0 = Bmm + (size_t)j0 * APITCH;
  const float* br1 = Bmm + (size_t)j1 * APITCH;
  const float* wdbase = W_e1 + 284 * E1OUT;  // rows 284..304, e-contiguous

  float z0[16], z1[16];
#pragma unroll
  for (int c = 0; c < 16; ++c) { z0[c] = 0.0f; z1[c] = 0.0f; }

#pragma unroll 1
  for (int s = 0; s < 10; ++s) {
    int e = lane + 64 * s;
    bool act = (e < E1OUT);
    int ec = act ? e : 0;

    float h0 = ar0[e] + br0[e];
    float h1 = ar1[e] + br1[e];
#pragma unroll
    for (int t = 0; t < 21; ++t) {
      float w = wdbase[t * E1OUT + ec];  // coalesced: lanes hit consecutive e
      h0 += df0[t] * w;
      h1 += df1[t] * w;
    }
    float hs0 = act ? siluf(h0) : 0.0f;
    float hs1 = act ? siluf(h1) : 0.0f;

    const float4* w2r = (const float4*)(W_e2 + (size_t)ec * 16);
    float4 w2a = w2r[0], w2b = w2r[1], w2c = w2r[2], w2d = w2r[3];
    z0[0] += hs0 * w2a.x;  z0[1] += hs0 * w2a.y;  z0[2] += hs0 * w2a.z;  z0[3] += hs0 * w2a.w;
    z0[4] += hs0 * w2b.x;  z0[5] += hs0 * w2b.y;  z0[6] += hs0 * w2b.z;  z0[7] += hs0 * w2b.w;
    z0[8] += hs0 * w2c.x;  z0[9] += hs0 * w2c.y;  z0[10] += hs0 * w2c.z; z0[11] += hs0 * w2c.w;
    z0[12] += hs0 * w2d.x; z0[13] += hs0 * w2d.y; z0[14] += hs0 * w2d.z; z0[15] += hs0 * w2d.w;
    z1[0] += hs1 * w2a.x;  z1[1] += hs1 * w2a.y;  z1[2] += hs1 * w2a.z;  z1[3] += hs1 * w2a.w;
    z1[4] += hs1 * w2b.x;  z1[5] += hs1 * w2b.y;  z1[6] += hs1 * w2b.z;  z1[7] += hs1 * w2b.w;
    z1[8] += hs1 * w2c.x;  z1[9] += hs1 * w2c.y;  z1[10] += hs1 * w2c.z; z1[11] += hs1 * w2c.w;
    z1[12] += hs1 * w2d.x; z1[13] += hs1 * w2d.y; z1[14] += hs1 * w2d.z; z1[15] += hs1 * w2d.w;
  }

  // butterfly-reduce each (ed,c); lane ed*16+c keeps its total
  float msel = 0.0f;
#pragma unroll
  for (int c = 0; c < 16; ++c) {
    float v = z0[c];
#pragma unroll
    for (int off = 32; off >= 1; off >>= 1) v += __shfl_xor(v, off, 64);
    if (lane == c) msel = v;
  }
#pragma unroll
  for (int c = 0; c < 16; ++c) {
    float v = z1[c];
#pragma unroll
    for (int off = 32; off >= 1; off >>= 1) v += __shfl_xor(v, off, 64);
    if (lane == 16 + c) msel = v;
  }
  if (lane < 32) {
    int isel = (lane < 16) ? i0 : i1;
    float m = siluf(msel + b_e2[lane & 15]);
    atomicAdd(&m_i[(size_t)isel * 16 + (lane & 15)], m);
  }
}

// ---------------------------------------------------------------------------
// LayerNorm + concat m_i -> node_in[32768][160]  (unchanged)
// ---------------------------------------------------------------------------
__global__ __launch_bounds__(256) void node_prep(const float* __restrict__ feats,
                                                 const float* __restrict__ m_i,
                                                 const float* __restrict__ ln_g,
                                                 const float* __restrict__ ln_b,
                                                 float* __restrict__ node_in) {
  int wave = threadIdx.x >> 6, lane = threadIdx.x & 63;
  int i = blockIdx.x * 4 + wave;
  const float* fr = feats + (size_t)i * DD;
  float x0 = fr[lane];
  float x1 = fr[lane + 64];
  float x2 = (lane < 14) ? fr[lane + 128] : 0.0f;
  float s = x0 + x1 + x2;
#pragma unroll
  for (int off = 32; off >= 1; off >>= 1) s += __shfl_xor(s, off, 64);
  float mu = s / 142.0f;
  float d0 = x0 - mu, d1 = x1 - mu, d2 = (lane < 14) ? (x2 - mu) : 0.0f;
  float ss = d0 * d0 + d1 * d1 + d2 * d2;
#pragma unroll
  for (int off = 32; off >= 1; off >>= 1) ss += __shfl_xor(ss, off, 64);
  float var = ss / 142.0f;
  float rstd = 1.0f / sqrtf(var + 1e-5f);
  float* o = node_in + (size_t)i * 160;
  o[lane] = d0 * rstd * ln_g[lane] + ln_b[lane];
  o[lane + 64] = d1 * rstd * ln_g[lane + 64] + ln_b[lane + 64];
  if (lane < 14) o[lane + 128] = d2 * rstd * ln_g[lane + 128] + ln_b[lane + 128];
  if (lane < 16) o[142 + lane] = m_i[i * 16 + lane];
}

// ---------------------------------------------------------------------------
// Masked mean pool fused with head -> f32 emb accumulator (unchanged)
// ---------------------------------------------------------------------------
__global__ __launch_bounds__(256) void pool_kernel(const float* __restrict__ node_out,
                                                   const float* __restrict__ W_out,
                                                   const float* __restrict__ b_out,
                                                   float* __restrict__ emb) {
  int b = blockIdx.x, chunk = blockIdx.y;
  int d = threadIdx.x;
  float acc = 0.0f;
  if (d < DD) {
    const float* base = node_out + ((size_t)(b * NN + chunk * 256)) * 144 + d;
    for (int n = 0; n < 256; ++n) acc += base[(size_t)n * 144];
    acc = acc * W_out[d] * (1.0f / 2048.0f);
  }
  __shared__ float red[256];
  red[threadIdx.x] = acc;
  __syncthreads();
  for (int off = 128; off >= 1; off >>= 1) {
    if (threadIdx.x < off) red[threadIdx.x] += red[threadIdx.x + off];
    __syncthreads();
  }
  if (threadIdx.x == 0) {
    float v = red[0];
    if (chunk == 0) v += b_out[0];
    atomicAdd(&emb[b], v);
  }
}

__global__ void finalize_kernel(const float* __restrict__ emb, float* __restrict__ outp) {
  int t = threadIdx.x;
  if (t < NB) outp[t] = emb[t];
}

// ---------------------------------------------------------------------------
extern "C" void kernel_launch(void* const* d_in, const int* in_sizes, int n_in,
                              void* d_out, int out_size, void* d_ws, size_t ws_size,
                              hipStream_t stream) {
  const float* feats = (const float*)d_in[0];
  const float* coors = (const float*)d_in[1];
  const float* W_e1 = (const float*)d_in[3];
  const float* b_e1 = (const float*)d_in[4];
  const float* W_e2 = (const float*)d_in[5];
  const float* b_e2 = (const float*)d_in[6];
  const float* ln_g = (const float*)d_in[11];
  const float* ln_b = (const float*)d_in[12];
  const float* W_n1 = (const float*)d_in[13];
  const float* b_n1 = (const float*)d_in[14];
  const float* W_n2 = (const float*)d_in[15];
  const float* b_n2 = (const float*)d_in[16];
  const float* W_out = (const float*)d_in[17];
  const float* b_out = (const float*)d_in[18];
  float* out = (float*)d_out;

  char* ws = (char*)d_ws;
  const size_t OFF_IDX = 0;
  const size_t OFF_DIST = 1310720;
  const size_t OFF_MI = 2621440;
  const size_t OFF_AP = 4718592;
  const size_t OFF_BM = 88604672;
  const size_t OFF_NIN = OFF_AP;              // reuse after edge kernel
  const size_t OFF_HN = OFF_AP + 20971520;
  const size_t OFF_NOUT = OFF_HN + 37748736;
  const size_t OFF_EMB = 172490752;

  int* idx = (int*)(ws + OFF_IDX);
  float* dist = (float*)(ws + OFF_DIST);
  float* m_i = (float*)(ws + OFF_MI);
  float* Ap = (float*)(ws + OFF_AP);
  float* Bm = (float*)(ws + OFF_BM);
  float* node_in = (float*)(ws + OFF_NIN);
  float* hnode = (float*)(ws + OFF_HN);
  float* node_out = (float*)(ws + OFF_NOUT);
  float* emb = (float*)(ws + OFF_EMB);

  hipMemsetAsync(m_i, 0, (size_t)NNODES * 16 * 4, stream);
  hipMemsetAsync(emb, 0, (size_t)NB * 4, stream);

  knn_kernel<<<dim3(NB * 512), dim3(256), 0, stream>>>(coors, idx, dist);

  brute_lin<<<dim3(NNODES / 8), dim3(256), 0, stream>>>(
      feats, DD, DD, W_e1, E1OUT, 0, E1OUT, b_e1, nullptr, 0, Ap, APITCH, 0);
  brute_lin<<<dim3(NNODES / 8), dim3(256), 0, stream>>>(
      feats, DD, DD, W_e1, E1OUT, 142, E1OUT, nullptr, nullptr, 0, Bm, APITCH, 0);

  edge_v6<<<dim3(NEDGES / 16), dim3(512), 0, stream>>>(
      Ap, Bm, idx, dist, W_e1, W_e2, b_e2, m_i);

  node_prep<<<dim3(NNODES / 4), dim3(256), 0, stream>>>(feats, m_i, ln_g, ln_b, node_in);

  brute_lin<<<dim3(NNODES / 8), dim3(256), 0, stream>>>(
      node_in, 160, 158, W_n1, 284, 0, 284, b_n1, nullptr, 0, hnode, 288, 1);
  brute_lin<<<dim3(NNODES / 8), dim3(256), 0, stream>>>(
      hnode, 288, 284, W_n2, DD, 0, DD, b_n2, feats, DD, node_out, 144, 0);

  pool_kernel<<<dim3(NB, 8), dim3(256), 0, stream>>>(node_out, W_out, b_out, emb);

  finalize_kernel<<<dim3(1), dim3(64), 0, stream>>>(emb, out);
}